// Round 22
// baseline (46.126 us; speedup 1.0000x reference)
//
#include <hip/hip_runtime.h>

#define H 256
#define SEQ 2048
#define NBATCH 64
#define M_TOTAL (NBATCH * SEQ)   // 131072 rows
#define BM 32                    // rows per tile
#define TILES 8                  // tiles per block
#define GRID (M_TOTAL / BM / TILES)  // 512 = 2 blocks/CU, one round

using bf16x8 = __attribute__((ext_vector_type(8))) short;
using f32x4  = __attribute__((ext_vector_type(4))) float;

__device__ __forceinline__ unsigned short f2bf(float x) {
    union { float f; unsigned u; } v; v.f = x;
    unsigned r = v.u + 0x7fffu + ((v.u >> 16) & 1u);   // RNE
    return (unsigned short)(r >> 16);
}

__device__ __forceinline__ bf16x8 gload16(const void* p) {
    bf16x8 r;
    asm volatile("global_load_dwordx4 %0, %1, off" : "=v"(r) : "v"(p));
    return r;
}
__device__ __forceinline__ void gstore(void* p, float v) {
    asm volatile("global_store_dword %0, %1, off" :: "v"(p), "v"(v) : "memory");
}
__device__ __forceinline__ void gload_lds16(const void* g, void* l) {
    __builtin_amdgcn_global_load_lds(
        (const __attribute__((address_space(1))) void*)g,
        (__attribute__((address_space(3))) void*)l, 16, 0, 0);
}
#define SB0() __builtin_amdgcn_sched_barrier(0)

// ------- prep 1a: partial[g][d] = sum_{c in g-slice} q[c]*W2[c,d]  (16 blocks) -------
// Parallel form is load-bearing: a single-block serial qpb loop (R19) is a ~4us
// latency chain that gates fused_main.
__global__ __launch_bounds__(256) void prep_qpb1(const float* __restrict__ q,
                                                 const float* __restrict__ W2,
                                                 float* __restrict__ partial) {
    const int g = blockIdx.x;      // 0..15
    const int t = threadIdx.x;     // d
    float s = 0.f;
#pragma unroll
    for (int i = 0; i < 16; ++i) {
        int c = g * 16 + i;
        s = fmaf(q[c], W2[c * H + t], s);
    }
    partial[g * H + t] = s;
}

// ------- prep 1b+2: blocks 0..31 pack W1 (RNE bf16); block 32 reduces qpb ------------
// W1 pack granule(ct 0..15, ks 0..7)[lane]: elem j = W1bf[ks*32+(lane>>4)*8+j][ct*16+(lane&15)]
__global__ __launch_bounds__(256) void prep_misc(const float* __restrict__ W1,
                                                 unsigned short* __restrict__ Bpack,
                                                 const float* __restrict__ partial,
                                                 const float* __restrict__ b1,
                                                 const float* __restrict__ b2,
                                                 float* __restrict__ qpb) {
    if (blockIdx.x < 32) {
        int tid = blockIdx.x * 256 + threadIdx.x;  // (ct,ks,lane)
        int ct = tid >> 9;
        int ks = (tid >> 6) & 7;
        int l  = tid & 63;
        bf16x8 hi;
#pragma unroll
        for (int j = 0; j < 8; ++j) {
            int kk = ks * 32 + ((l >> 4) & 3) * 8 + j;
            int nn = ct * 16 + (l & 15);
            hi[j] = (short)f2bf(W1[kk * H + nn]);
        }
        ((bf16x8*)Bpack)[(ct * 8 + ks) * 64 + l] = hi;
    } else {
        const int t = threadIdx.x;
        float s = b1[t] + b2[t];
#pragma unroll
        for (int g = 0; g < 16; ++g) s += partial[g * H + t];
        qpb[t] = s;
    }
}

// ---------------- main (byte-identical to the R21 winner, 46.1 us) ----------------
// n-split 4: 256 threads = 4 waves; wave w owns n in [w*64, w*64+64) (4 ct), all
// 32 m-rows. All waves read IDENTICAL k-fragments, so halving the wave count
// halves total LDS-read traffic (the R15 structure's binding cost). W1 slice is
// 128 VGPR -> needs the 256-VGPR budget at 2 waves/EU: __launch_bounds__(256,2).
// In-loop cvt structure preserved (R14/R16-R18: cvt-free loops trip the
// allocator into a 64-VGPR spill of w1; the cvts are load-bearing). k: f32 via
// global_load_lds, double-buffered, issue-early at ks=0 / drain-late after the
// epilogue. Swizzle ^(r&7) on 16B slots, both sides.
__global__ __launch_bounds__(256, 2) void fused_main(const float* __restrict__ kin,
                                                     const unsigned short* __restrict__ Bpack,
                                                     const float* __restrict__ qpb,
                                                     const float* __restrict__ Vp,
                                                     float* __restrict__ out_scores) {
    __shared__ __align__(16) unsigned char Kb[2][32768];   // f32 [32][256] x2
    __shared__ float part[2][4][32];
    __shared__ __align__(16) float qlds[256];
    __shared__ __align__(16) float vlds[256];

    const int t    = threadIdx.x;        // 0..255
    const int wave = t >> 6;             // 0..3 = n-group (64 cols)
    const int lane = t & 63;
    const int lhi  = lane >> 4;
    const int llo  = lane & 15;
    const int base = blockIdx.x * (BM * TILES);

    // qpb/V -> LDS (plain loads; compiler drains them before first barrier)
    if (t < 64)       *(f32x4*)(qlds + t * 4)        = *(const f32x4*)(qpb + t * 4);
    else if (t < 128) *(f32x4*)(vlds + (t - 64) * 4) = *(const f32x4*)(Vp + (t - 64) * 4);

    // ---- W1 -> registers, once (wave's 4 ct-slices x 8 ks = 128 VGPR) ----
    bf16x8 w1[4][8];
    const char* bb = (const char*)Bpack + (size_t)lane * 16;
#pragma unroll
    for (int c = 0; c < 4; ++c)
#pragma unroll
        for (int ks = 0; ks < 8; ++ks)
            w1[c][ks] = gload16(bb + (size_t)((wave * 4 + c) * 8 + ks) * 1024);

    // one GLD stages one full row: row = i*4+wave (uniform), lane = 16B col.
#define STAGEG(B, TB)                                                            \
    do {                                                                         \
        _Pragma("unroll")                                                        \
        for (int i = 0; i < 8; ++i) {                                            \
            int r = i * 4 + wave;                                                \
            const float* g = kin + (size_t)((TB) + r) * H + ((lane ^ (r & 7)) << 2); \
            gload_lds16(g, &Kb[B][r * 1024]);                                    \
        }                                                                        \
    } while (0)

    STAGEG(0, base);
    asm volatile("s_waitcnt vmcnt(0)");   // W1 + tile0 staged
    SB0();
    __builtin_amdgcn_s_barrier();

#pragma unroll 1
    for (int j = 0; j < TILES; ++j) {
        const unsigned char* Kc = &Kb[j & 1][0];

        f32x4 acc[4][2];   // [ct][mt]
#pragma unroll
        for (int a = 0; a < 4; ++a)
#pragma unroll
            for (int b = 0; b < 2; ++b) acc[a][b] = (f32x4){0.f, 0.f, 0.f, 0.f};

#pragma unroll
        for (int ks = 0; ks < 8; ++ks) {
            if (ks == 0 && j < TILES - 1)
                STAGEG((j + 1) & 1, base + (j + 1) * BM);   // issue-early, drain late

            const int s0 = ks * 8 + lhi * 2;
            const int x  = llo & 7;
            const f32x4 fa0 = *(const f32x4*)(Kc + (llo     ) * 1024 + ((s0    ) ^ x) * 16);
            const f32x4 fb0 = *(const f32x4*)(Kc + (llo     ) * 1024 + ((s0 + 1) ^ x) * 16);
            const f32x4 fa1 = *(const f32x4*)(Kc + (16 + llo) * 1024 + ((s0    ) ^ x) * 16);
            const f32x4 fb1 = *(const f32x4*)(Kc + (16 + llo) * 1024 + ((s0 + 1) ^ x) * 16);
            union KU { unsigned u[4]; bf16x8 v; } k0, k1;
            asm("v_cvt_pk_bf16_f32 %0, %1, %2" : "=v"(k0.u[0]) : "v"(fa0[0]), "v"(fa0[1]));
            asm("v_cvt_pk_bf16_f32 %0, %1, %2" : "=v"(k0.u[1]) : "v"(fa0[2]), "v"(fa0[3]));
            asm("v_cvt_pk_bf16_f32 %0, %1, %2" : "=v"(k0.u[2]) : "v"(fb0[0]), "v"(fb0[1]));
            asm("v_cvt_pk_bf16_f32 %0, %1, %2" : "=v"(k0.u[3]) : "v"(fb0[2]), "v"(fb0[3]));
            asm("v_cvt_pk_bf16_f32 %0, %1, %2" : "=v"(k1.u[0]) : "v"(fa1[0]), "v"(fa1[1]));
            asm("v_cvt_pk_bf16_f32 %0, %1, %2" : "=v"(k1.u[1]) : "v"(fa1[2]), "v"(fa1[3]));
            asm("v_cvt_pk_bf16_f32 %0, %1, %2" : "=v"(k1.u[2]) : "v"(fb1[0]), "v"(fb1[1]));
            asm("v_cvt_pk_bf16_f32 %0, %1, %2" : "=v"(k1.u[3]) : "v"(fb1[2]), "v"(fb1[3]));

#pragma unroll
            for (int c = 0; c < 4; ++c) {
                acc[c][0] = __builtin_amdgcn_mfma_f32_16x16x32_bf16(w1[c][ks], k0.v, acc[c][0], 0, 0, 0);
                acc[c][1] = __builtin_amdgcn_mfma_f32_16x16x32_bf16(w1[c][ks], k1.v, acc[c][1], 0, 0, 0);
            }
        }

        // ---- epilogue: tanh, *V, in-lane reduce over wave's 64 n ----
        float sm0 = 0.f, sm1 = 0.f;
#pragma unroll
        for (int c = 0; c < 4; ++c) {
            f32x4 qv = *(const f32x4*)(qlds + wave * 64 + c * 16 + lhi * 4);
            f32x4 vv = *(const f32x4*)(vlds + wave * 64 + c * 16 + lhi * 4);
#pragma unroll
            for (int i = 0; i < 4; ++i) {
                float x0 = acc[c][0][i] + qv[i];
                float e0 = __expf(2.f * x0);
                sm0 += (1.f - 2.f * __builtin_amdgcn_rcpf(e0 + 1.f)) * vv[i];
                float x1 = acc[c][1][i] + qv[i];
                float e1 = __expf(2.f * x1);
                sm1 += (1.f - 2.f * __builtin_amdgcn_rcpf(e1 + 1.f)) * vv[i];
            }
        }
        sm0 += __shfl_xor(sm0, 16, 64); sm0 += __shfl_xor(sm0, 32, 64);
        sm1 += __shfl_xor(sm1, 16, 64); sm1 += __shfl_xor(sm1, 32, 64);
        if (lane < 16) {
            part[j & 1][wave][llo]      = sm0;
            part[j & 1][wave][16 + llo] = sm1;
        }

        // drain tile j+1's GLDs (issued a full tile ago) + prior store; swap
        asm volatile("s_waitcnt vmcnt(0)");
        asm volatile("s_waitcnt lgkmcnt(0)" ::: "memory");
        __builtin_amdgcn_s_barrier();
        SB0();

        if (t < BM) {
            float r = part[j & 1][0][t] + part[j & 1][1][t]
                    + part[j & 1][2][t] + part[j & 1][3][t];
            gstore(out_scores + base + j * BM + t, r);
        }
    }
#undef STAGEG
}

// ---------------- softmax over seq axis, in-place on d_out ----------------
// 1024 threads/block (was 256): 2 elements/thread, 16-wave two-stage reduce.
__global__ __launch_bounds__(1024) void softmax_kernel(float* __restrict__ out) {
    const int b = blockIdx.x;
    const int t = threadIdx.x;        // 0..1023
    float* row = out + b * SEQ;
    float v0 = row[t], v1 = row[t + 1024];
    float mx = fmaxf(v0, v1);
#pragma unroll
    for (int off = 1; off < 64; off <<= 1) mx = fmaxf(mx, __shfl_xor(mx, off, 64));
    __shared__ float redm[16], reds[16];
    const int lane = t & 63, w = t >> 6;
    if (lane == 0) redm[w] = mx;
    __syncthreads();
    mx = redm[0];
#pragma unroll
    for (int i = 1; i < 16; ++i) mx = fmaxf(mx, redm[i]);
    float e0 = __expf(v0 - mx), e1 = __expf(v1 - mx);
    float sum = e0 + e1;
#pragma unroll
    for (int off = 1; off < 64; off <<= 1) sum += __shfl_xor(sum, off, 64);
    if (lane == 0) reds[w] = sum;
    __syncthreads();
    float tot = reds[0];
#pragma unroll
    for (int i = 1; i < 16; ++i) tot += reds[i];
    const float inv = 1.0f / tot;
    row[t]        = e0 * inv;
    row[t + 1024] = e1 * inv;
}

extern "C" void kernel_launch(void* const* d_in, const int* in_sizes, int n_in,
                              void* d_out, int out_size, void* d_ws, size_t ws_size,
                              hipStream_t stream) {
    const float* q  = (const float*)d_in[0];
    const float* k  = (const float*)d_in[1];
    const float* W1 = (const float*)d_in[2];
    const float* b1 = (const float*)d_in[3];
    const float* W2 = (const float*)d_in[4];
    const float* b2 = (const float*)d_in[5];
    const float* V  = (const float*)d_in[6];
    // d_in[7] = bv: softmax-invariant scalar, skipped.
    float* out = (float*)d_out;

    float* qpb     = (float*)d_ws;                                   // 1 KB
    float* partial = (float*)((char*)d_ws + 1024);                   // 16 KB
    unsigned short* Bpack = (unsigned short*)((char*)d_ws + 17408);  // 128 KB

    prep_qpb1<<<16, 256, 0, stream>>>(q, W2, partial);
    prep_misc<<<33, 256, 0, stream>>>(W1, Bpack, partial, b1, b2, qpb);
    fused_main<<<GRID, 256, 0, stream>>>(k, Bpack, qpb, V, out);
    softmax_kernel<<<NBATCH, 1024, 0, stream>>>(out);
}

// Round 23
// 43.831 us; speedup vs baseline: 1.0524x; 1.0524x over previous
//
#include <hip/hip_runtime.h>

#define H 256
#define SEQ 2048
#define NBATCH 64
#define M_TOTAL (NBATCH * SEQ)   // 131072 rows
#define BM 32                    // rows per tile
#define TILES 8                  // tiles per block
#define GRID (M_TOTAL / BM / TILES)  // 512 = 2 blocks/CU, one round

using bf16x8 = __attribute__((ext_vector_type(8))) short;
using f32x4  = __attribute__((ext_vector_type(4))) float;

__device__ __forceinline__ unsigned short f2bf(float x) {
    union { float f; unsigned u; } v; v.f = x;
    unsigned r = v.u + 0x7fffu + ((v.u >> 16) & 1u);   // RNE
    return (unsigned short)(r >> 16);
}

__device__ __forceinline__ bf16x8 gload16(const void* p) {
    bf16x8 r;
    asm volatile("global_load_dwordx4 %0, %1, off" : "=v"(r) : "v"(p));
    return r;
}
__device__ __forceinline__ void gstore(void* p, float v) {
    asm volatile("global_store_dword %0, %1, off" :: "v"(p), "v"(v) : "memory");
}
__device__ __forceinline__ void gload_lds16(const void* g, void* l) {
    __builtin_amdgcn_global_load_lds(
        (const __attribute__((address_space(1))) void*)g,
        (__attribute__((address_space(3))) void*)l, 16, 0, 0);
}
#define SB0() __builtin_amdgcn_sched_barrier(0)

// ------- prep (ONE launch, 48 fully-parallel blocks) -------
// blocks 0..31:  pack W1 (RNE bf16) into MFMA fragment order:
//   granule(ct 0..15, ks 0..7)[lane]: elem j = W1bf[ks*32+(lane>>4)*8+j][ct*16+(lane&15)]
// blocks 32..47: partial[g][d] = sum_{c in g-slice} q[c]*W2[c,d]
//   (16-way parallel; final reduction is folded into fused_main's qlds setup)
__global__ __launch_bounds__(256) void prep_all(const float* __restrict__ W1,
                                                unsigned short* __restrict__ Bpack,
                                                const float* __restrict__ q,
                                                const float* __restrict__ W2,
                                                float* __restrict__ partial) {
    if (blockIdx.x < 32) {
        int tid = blockIdx.x * 256 + threadIdx.x;  // (ct,ks,lane)
        int ct = tid >> 9;
        int ks = (tid >> 6) & 7;
        int l  = tid & 63;
        bf16x8 hi;
#pragma unroll
        for (int j = 0; j < 8; ++j) {
            int kk = ks * 32 + ((l >> 4) & 3) * 8 + j;
            int nn = ct * 16 + (l & 15);
            hi[j] = (short)f2bf(W1[kk * H + nn]);
        }
        ((bf16x8*)Bpack)[(ct * 8 + ks) * 64 + l] = hi;
    } else {
        const int g = blockIdx.x - 32;  // 0..15
        const int t = threadIdx.x;      // d
        float s = 0.f;
#pragma unroll
        for (int i = 0; i < 16; ++i) {
            int c = g * 16 + i;
            s = fmaf(q[c], W2[c * H + t], s);
        }
        partial[g * H + t] = s;
    }
}

// ---------------- main (R21 winner body + inline qpb reduction) ----------------
// n-split 4: 256 threads = 4 waves; wave w owns n in [w*64, w*64+64) (4 ct), all
// 32 m-rows. All waves read IDENTICAL k-fragments, so fewer waves = less total
// LDS-read traffic (the binding cost). W1 slice is 128 VGPR -> needs the
// 256-VGPR budget at 2 waves/EU: __launch_bounds__(256,2).
// In-loop cvt structure preserved (R14/R16-R18: cvt-free loops trip the
// allocator into a 64-VGPR spill of w1; the cvts are load-bearing). k: f32 via
// global_load_lds, double-buffered, issue-early at ks=0 / drain-late after the
// epilogue. Swizzle ^(r&7) on 16B slots, both sides. All manual waits are
// vmcnt(0), so the extra compiler-tracked qpb loads below are ledger-safe.
__global__ __launch_bounds__(256, 2) void fused_main(const float* __restrict__ kin,
                                                     const unsigned short* __restrict__ Bpack,
                                                     const float* __restrict__ partial,
                                                     const float* __restrict__ b1,
                                                     const float* __restrict__ b2,
                                                     const float* __restrict__ Vp,
                                                     float* __restrict__ out_scores) {
    __shared__ __align__(16) unsigned char Kb[2][32768];   // f32 [32][256] x2
    __shared__ float part[2][4][32];
    __shared__ __align__(16) float qlds[256];
    __shared__ __align__(16) float vlds[256];

    const int t    = threadIdx.x;        // 0..255
    const int wave = t >> 6;             // 0..3 = n-group (64 cols)
    const int lane = t & 63;
    const int lhi  = lane >> 4;
    const int llo  = lane & 15;
    const int base = blockIdx.x * (BM * TILES);

    // qpb = b1 + b2 + sum_g partial[g]  (wave 0, 18 f32x4 loads/thread, L3-hot)
    if (t < 64) {
        f32x4 s = *(const f32x4*)(b1 + t * 4);
        s += *(const f32x4*)(b2 + t * 4);
#pragma unroll
        for (int g = 0; g < 16; ++g) s += *(const f32x4*)(partial + g * H + t * 4);
        *(f32x4*)(qlds + t * 4) = s;
    } else if (t < 128) {
        *(f32x4*)(vlds + (t - 64) * 4) = *(const f32x4*)(Vp + (t - 64) * 4);
    }

    // ---- W1 -> registers, once (wave's 4 ct-slices x 8 ks = 128 VGPR) ----
    bf16x8 w1[4][8];
    const char* bb = (const char*)Bpack + (size_t)lane * 16;
#pragma unroll
    for (int c = 0; c < 4; ++c)
#pragma unroll
        for (int ks = 0; ks < 8; ++ks)
            w1[c][ks] = gload16(bb + (size_t)((wave * 4 + c) * 8 + ks) * 1024);

    // one GLD stages one full row: row = i*4+wave (uniform), lane = 16B col.
#define STAGEG(B, TB)                                                            \
    do {                                                                         \
        _Pragma("unroll")                                                        \
        for (int i = 0; i < 8; ++i) {                                            \
            int r = i * 4 + wave;                                                \
            const float* g = kin + (size_t)((TB) + r) * H + ((lane ^ (r & 7)) << 2); \
            gload_lds16(g, &Kb[B][r * 1024]);                                    \
        }                                                                        \
    } while (0)

    STAGEG(0, base);
    asm volatile("s_waitcnt vmcnt(0)");   // W1 + tile0 + qpb loads landed
    SB0();
    __builtin_amdgcn_s_barrier();

#pragma unroll 1
    for (int j = 0; j < TILES; ++j) {
        const unsigned char* Kc = &Kb[j & 1][0];

        f32x4 acc[4][2];   // [ct][mt]
#pragma unroll
        for (int a = 0; a < 4; ++a)
#pragma unroll
            for (int b = 0; b < 2; ++b) acc[a][b] = (f32x4){0.f, 0.f, 0.f, 0.f};

#pragma unroll
        for (int ks = 0; ks < 8; ++ks) {
            if (ks == 0 && j < TILES - 1)
                STAGEG((j + 1) & 1, base + (j + 1) * BM);   // issue-early, drain late

            const int s0 = ks * 8 + lhi * 2;
            const int x  = llo & 7;
            const f32x4 fa0 = *(const f32x4*)(Kc + (llo     ) * 1024 + ((s0    ) ^ x) * 16);
            const f32x4 fb0 = *(const f32x4*)(Kc + (llo     ) * 1024 + ((s0 + 1) ^ x) * 16);
            const f32x4 fa1 = *(const f32x4*)(Kc + (16 + llo) * 1024 + ((s0    ) ^ x) * 16);
            const f32x4 fb1 = *(const f32x4*)(Kc + (16 + llo) * 1024 + ((s0 + 1) ^ x) * 16);
            union KU { unsigned u[4]; bf16x8 v; } k0, k1;
            asm("v_cvt_pk_bf16_f32 %0, %1, %2" : "=v"(k0.u[0]) : "v"(fa0[0]), "v"(fa0[1]));
            asm("v_cvt_pk_bf16_f32 %0, %1, %2" : "=v"(k0.u[1]) : "v"(fa0[2]), "v"(fa0[3]));
            asm("v_cvt_pk_bf16_f32 %0, %1, %2" : "=v"(k0.u[2]) : "v"(fb0[0]), "v"(fb0[1]));
            asm("v_cvt_pk_bf16_f32 %0, %1, %2" : "=v"(k0.u[3]) : "v"(fb0[2]), "v"(fb0[3]));
            asm("v_cvt_pk_bf16_f32 %0, %1, %2" : "=v"(k1.u[0]) : "v"(fa1[0]), "v"(fa1[1]));
            asm("v_cvt_pk_bf16_f32 %0, %1, %2" : "=v"(k1.u[1]) : "v"(fa1[2]), "v"(fa1[3]));
            asm("v_cvt_pk_bf16_f32 %0, %1, %2" : "=v"(k1.u[2]) : "v"(fb1[0]), "v"(fb1[1]));
            asm("v_cvt_pk_bf16_f32 %0, %1, %2" : "=v"(k1.u[3]) : "v"(fb1[2]), "v"(fb1[3]));

#pragma unroll
            for (int c = 0; c < 4; ++c) {
                acc[c][0] = __builtin_amdgcn_mfma_f32_16x16x32_bf16(w1[c][ks], k0.v, acc[c][0], 0, 0, 0);
                acc[c][1] = __builtin_amdgcn_mfma_f32_16x16x32_bf16(w1[c][ks], k1.v, acc[c][1], 0, 0, 0);
            }
        }

        // ---- epilogue: tanh, *V, in-lane reduce over wave's 64 n ----
        float sm0 = 0.f, sm1 = 0.f;
#pragma unroll
        for (int c = 0; c < 4; ++c) {
            f32x4 qv = *(const f32x4*)(qlds + wave * 64 + c * 16 + lhi * 4);
            f32x4 vv = *(const f32x4*)(vlds + wave * 64 + c * 16 + lhi * 4);
#pragma unroll
            for (int i = 0; i < 4; ++i) {
                float x0 = acc[c][0][i] + qv[i];
                float e0 = __expf(2.f * x0);
                sm0 += (1.f - 2.f * __builtin_amdgcn_rcpf(e0 + 1.f)) * vv[i];
                float x1 = acc[c][1][i] + qv[i];
                float e1 = __expf(2.f * x1);
                sm1 += (1.f - 2.f * __builtin_amdgcn_rcpf(e1 + 1.f)) * vv[i];
            }
        }
        sm0 += __shfl_xor(sm0, 16, 64); sm0 += __shfl_xor(sm0, 32, 64);
        sm1 += __shfl_xor(sm1, 16, 64); sm1 += __shfl_xor(sm1, 32, 64);
        if (lane < 16) {
            part[j & 1][wave][llo]      = sm0;
            part[j & 1][wave][16 + llo] = sm1;
        }

        // drain tile j+1's GLDs (issued a full tile ago) + prior store; swap
        asm volatile("s_waitcnt vmcnt(0)");
        asm volatile("s_waitcnt lgkmcnt(0)" ::: "memory");
        __builtin_amdgcn_s_barrier();
        SB0();

        if (t < BM) {
            float r = part[j & 1][0][t] + part[j & 1][1][t]
                    + part[j & 1][2][t] + part[j & 1][3][t];
            gstore(out_scores + base + j * BM + t, r);
        }
    }
#undef STAGEG
}

// ---------------- softmax over seq axis, in-place on d_out ----------------
// 1024 threads/block: 2 elements/thread, 16-wave two-stage reduce.
__global__ __launch_bounds__(1024) void softmax_kernel(float* __restrict__ out) {
    const int b = blockIdx.x;
    const int t = threadIdx.x;        // 0..1023
    float* row = out + b * SEQ;
    float v0 = row[t], v1 = row[t + 1024];
    float mx = fmaxf(v0, v1);
#pragma unroll
    for (int off = 1; off < 64; off <<= 1) mx = fmaxf(mx, __shfl_xor(mx, off, 64));
    __shared__ float redm[16], reds[16];
    const int lane = t & 63, w = t >> 6;
    if (lane == 0) redm[w] = mx;
    __syncthreads();
    mx = redm[0];
#pragma unroll
    for (int i = 1; i < 16; ++i) mx = fmaxf(mx, redm[i]);
    float e0 = __expf(v0 - mx), e1 = __expf(v1 - mx);
    float sum = e0 + e1;
#pragma unroll
    for (int off = 1; off < 64; off <<= 1) sum += __shfl_xor(sum, off, 64);
    if (lane == 0) reds[w] = sum;
    __syncthreads();
    float tot = reds[0];
#pragma unroll
    for (int i = 1; i < 16; ++i) tot += reds[i];
    const float inv = 1.0f / tot;
    row[t]        = e0 * inv;
    row[t + 1024] = e1 * inv;
}

extern "C" void kernel_launch(void* const* d_in, const int* in_sizes, int n_in,
                              void* d_out, int out_size, void* d_ws, size_t ws_size,
                              hipStream_t stream) {
    const float* q  = (const float*)d_in[0];
    const float* k  = (const float*)d_in[1];
    const float* W1 = (const float*)d_in[2];
    const float* b1 = (const float*)d_in[3];
    const float* W2 = (const float*)d_in[4];
    const float* b2 = (const float*)d_in[5];
    const float* V  = (const float*)d_in[6];
    // d_in[7] = bv: softmax-invariant scalar, skipped.
    float* out = (float*)d_out;

    float* partial = (float*)d_ws;                                   // 16 KB
    unsigned short* Bpack = (unsigned short*)((char*)d_ws + 16384);  // 128 KB

    prep_all<<<48, 256, 0, stream>>>(W1, Bpack, q, W2, partial);
    fused_main<<<GRID, 256, 0, stream>>>(k, Bpack, partial, b1, b2, V, out);
    softmax_kernel<<<NBATCH, 1024, 0, stream>>>(out);
}